// Round 3
// baseline (174.580 us; speedup 1.0000x reference)
//
#include <hip/hip_runtime.h>
#include <hip/hip_fp16.h>

#define NTREE  64
#define NFEAT  1024
#define NLEAF  64
#define NBATCH 32768
#define WAVES  4
#define THREADS 256
#define GRID   2048
#define WSTRIDE (GRID * WAVES)   // 8192 waves -> 4 rows each

// d[j] = sigmoid(x[b, fidx[t, j]]); layer k uses d[(2^k-1)+i] for parent i;
// child 2i *= d, child 2i+1 *= (1-d). prob = mu . pi[t]; probs[b][l][t] = mu[l].
__device__ __forceinline__ float sig1(float v) {
    return __builtin_amdgcn_rcpf(1.0f + __expf(-v));
}

__global__ __launch_bounds__(THREADS, 5)
void forest_kernel(const float* __restrict__ x,
                   const int*   __restrict__ fidx,
                   const float* __restrict__ pi,
                   float* __restrict__ prob,    // [B][T]
                   float* __restrict__ probs)   // [B][L][T]
{
    // srow: per-wave sigmoid row (16 KB). Its first 8 KB doubles as one-time
    // idx staging space (reclaimed after the second barrier).
    __shared__ float   srow[WAVES][NFEAT];   // 16 KB
    __shared__ __half2 pil[32 * NTREE];      // 8 KB, [k][t] = (pi[2k]-pi[2k+1], pi[2k+1])
                                             // total 24.4 KB -> 5 blocks/CU (VGPR-bound)

    const int tid  = threadIdx.x;
    const int wid  = tid >> 6;
    const int lane = tid & 63;               // lane == tree t

    // ---- one-time staging: packed idx byte-offset pairs + folded pi ----
    unsigned* idxp = reinterpret_cast<unsigned*>(&srow[0][0]);   // 2048 u32 = 8 KB
    for (int i = tid; i < 2048; i += THREADS) {
        int k = i >> 6, t = i & 63;
        unsigned v0 = (unsigned)fidx[t * 63 + 2 * k] << 2;
        unsigned v1 = (2 * k + 1 < 63) ? ((unsigned)fidx[t * 63 + 2 * k + 1] << 2) : 0u;
        idxp[i] = v0 | (v1 << 16);
    }
    for (int i = tid; i < 2048; i += THREADS) {
        int k = i >> 6, t = i & 63;
        float p1 = pi[t * 64 + 2 * k + 1];
        pil[i] = __floats2half2_rn(pi[t * 64 + 2 * k] - p1, p1);
    }
    __syncthreads();

    // Hoist packed gather offsets into 32 VGPRs (conflict-free [k][t] reads),
    // pre-adding this wave's srow byte base into BOTH halves (no carry: each
    // half stays < 16380 < 65536). srow sits at LDS offset 0, so a gather is
    // just extract -> ds_read.
    unsigned ioff[32];
    const unsigned basep = (unsigned)(wid * (NFEAT * 4)) * 0x10001u;
    #pragma unroll
    for (int k = 0; k < 32; ++k) ioff[k] = idxp[k * 64 + lane] + basep;
    __syncthreads();   // idxp region now safe to overwrite with sigmoid rows

    const int t = lane;
    char* swc = reinterpret_cast<char*>(&srow[0][0]);  // offsets carry wid base

#define OFF(j)  ((j) & 1 ? (ioff[(j) >> 1] >> 16) : (ioff[(j) >> 1] & 0xFFFFu))
#define GATH(j) (*reinterpret_cast<const float*>(swc + OFF(j)))

    int b = blockIdx.x * WAVES + wid;
    #pragma unroll 1
    for (int it = 0; it < NBATCH / WSTRIDE; ++it, b += WSTRIDE) {
        // ---- sigmoid current row -> this wave's private LDS row ----
        const float4* xr4 = reinterpret_cast<const float4*>(x + (size_t)b * NFEAT);
        float4* sr4 = reinterpret_cast<float4*>(&srow[wid][0]);
        #pragma unroll
        for (int i = 0; i < 4; ++i) {
            float4 v = xr4[lane + i * 64];
            sr4[lane + i * 64] =
                make_float4(sig1(v.x), sig1(v.y), sig1(v.z), sig1(v.w));
        }
        // same-wave DS is in-order; srow is wave-private -> no barrier needed.

        // ---- layers 0..4: in-place doubling, mu[0..31] ----
        float mu[32];
        mu[0] = 1.0f;
        #pragma unroll
        for (int k = 0; k < 5; ++k) {
            const int n = 1 << k;
            #pragma unroll
            for (int i = n - 1; i >= 0; --i) {
                float dv = GATH(n - 1 + i);
                float m  = mu[i];
                float a  = m * dv;
                mu[2 * i]     = a;
                mu[2 * i + 1] = m - a;
            }
        }

        // ---- final layer fused with coalesced stores + folded pi-dot ----
        float acc = 0.0f;
        float* pb = probs + (size_t)b * (NLEAF * NTREE) + t;
        #pragma unroll
        for (int i = 0; i < 32; ++i) {
            float dv = GATH(31 + i);
            float m  = mu[i];
            float a  = m * dv;            // leaf 2i
            float c  = m - a;             // leaf 2i+1
            pb[(2 * i) * NTREE]     = a;  // 64 lanes span t: 256B coalesced
            pb[(2 * i + 1) * NTREE] = c;
            float2 p = __half22float2(pil[i * 64 + t]);   // (dpi, spi), conflict-free
            acc = fmaf(m, fmaf(dv, p.x, p.y), acc);
        }
        prob[b * NTREE + t] = acc;
    }
#undef OFF
#undef GATH
}

extern "C" void kernel_launch(void* const* d_in, const int* in_sizes, int n_in,
                              void* d_out, int out_size, void* d_ws, size_t ws_size,
                              hipStream_t stream) {
    const float* x    = (const float*)d_in[0];
    const int*   fidx = (const int*)d_in[1];
    const float* pi   = (const float*)d_in[2];
    float* prob  = (float*)d_out;                              // B*T
    float* probs = (float*)d_out + (size_t)NBATCH * NTREE;     // B*L*T

    dim3 grid(GRID), block(THREADS);
    hipLaunchKernelGGL(forest_kernel, grid, block, 0, stream,
                       x, fidx, pi, prob, probs);
}

// Round 4
// 146.820 us; speedup vs baseline: 1.1891x; 1.1891x over previous
//
#include <hip/hip_runtime.h>
#include <hip/hip_fp16.h>

#define NTREE  64
#define NFEAT  1024
#define NLEAF  64
#define NBATCH 32768
#define WAVES  4
#define THREADS 256
#define GRID   1024                              // 4 blocks/CU x 256 CU: one round
#define ROWS_PER_WAVE (NBATCH / (GRID * WAVES))  // 8, exact

// d[j] = sigmoid(x[b, fidx[t, j]]); layer k uses d[(2^k-1)+i] for parent i;
// child 2i *= d, child 2i+1 *= (1-d). prob = mu . pi[t]; probs[b][l][t] = mu[l].
__device__ __forceinline__ float sig1(float v) {
    return __builtin_amdgcn_rcpf(1.0f + __expf(-v));
}

__global__ __launch_bounds__(THREADS, 4)
void forest_kernel(const float* __restrict__ x,
                   const int*   __restrict__ fidx,
                   const float* __restrict__ pi,
                   float* __restrict__ prob,    // [B][T]
                   float* __restrict__ probs)   // [B][L][T]
{
    __shared__ float          srow[WAVES][NFEAT]; // 16384 B (per-wave private row)
    __shared__ unsigned short idxl[63 * 64];      // 8064 B: [c][t] byte offsets
    __shared__ __half2        pil[32 * NTREE];    // 8192 B: [k][t] = (pi2k-pi2k1, pi2k1)
    // total 32640 B -> 4+ blocks/CU; VGPR capped at 128 by launch_bounds (no spill:
    // live set is mu[32] + addressing, ~80 regs)

    const int tid  = threadIdx.x;
    const int wid  = tid >> 6;
    const int lane = tid & 63;                    // lane == tree t

    // One-time staging (L2-resident inputs).
    for (int i = tid; i < 63 * 64; i += THREADS) {
        int t = i / 63, c = i - t * 63;           // fidx[t][c]
        idxl[c * 64 + t] = (unsigned short)(fidx[i] << 2);
    }
    for (int i = tid; i < 32 * 64; i += THREADS) {
        int t = i & 63, k = i >> 6;
        float p0 = pi[t * 64 + 2 * k], p1 = pi[t * 64 + 2 * k + 1];
        pil[k * 64 + t] = __floats2half2_rn(p0 - p1, p1);
    }
    __syncthreads();                              // only cross-wave sync in the kernel

    const int t = lane;
    const char* swc = reinterpret_cast<const char*>(&srow[wid][0]);
    float4* sr4 = reinterpret_cast<float4*>(&srow[wid][0]);

    int b = (blockIdx.x * WAVES + wid) * ROWS_PER_WAVE;
    #pragma unroll 1
    for (int it = 0; it < ROWS_PER_WAVE; ++it, ++b) {
        // Clobber keeps the loop-invariant idxl/pil LDS reads INSIDE the loop —
        // hoisting 95 values into VGPRs would spill at the 128-reg cap (R3 lesson).
        asm volatile("" ::: "memory");

        // ---- sigmoid(x[b,:]) -> this wave's private LDS row ----
        const float4* xr4 = reinterpret_cast<const float4*>(x + (size_t)b * NFEAT);
        #pragma unroll
        for (int i = 0; i < 4; ++i) {
            float4 v = xr4[lane + i * 64];
            sr4[lane + i * 64] =
                make_float4(sig1(v.x), sig1(v.y), sig1(v.z), sig1(v.w));
        }
        // srow is wave-private; same-wave LDS ordering handled by compiler waits.

        // ---- layers 0..4: in-place doubling, mu[0..31] ----
        float mu[32];
        mu[0] = 1.0f;
        #pragma unroll
        for (int k = 0; k < 5; ++k) {
            const int n = 1 << k;
            #pragma unroll
            for (int i = n - 1; i >= 0; --i) {
                float dv = *reinterpret_cast<const float*>(
                               swc + idxl[(n - 1 + i) * 64 + t]);
                float m  = mu[i];
                float a  = m * dv;
                mu[2 * i]     = a;
                mu[2 * i + 1] = m - a;
            }
        }

        // ---- final layer fused with coalesced stores + folded pi-dot ----
        float acc = 0.0f;
        float* pb = probs + (size_t)b * (NLEAF * NTREE) + t;
        #pragma unroll
        for (int i = 0; i < 32; ++i) {
            float dv = *reinterpret_cast<const float*>(
                           swc + idxl[(31 + i) * 64 + t]);
            float m  = mu[i];
            float a  = m * dv;            // leaf 2i
            float c  = m - a;             // leaf 2i+1
            pb[(2 * i) * NTREE]     = a;  // 64 lanes span t: 256B coalesced
            pb[(2 * i + 1) * NTREE] = c;
            float2 p = __half22float2(pil[i * 64 + t]);  // (dpi, spi), conflict-free
            acc = fmaf(m, fmaf(dv, p.x, p.y), acc);
        }
        prob[b * NTREE + t] = acc;
    }
}

extern "C" void kernel_launch(void* const* d_in, const int* in_sizes, int n_in,
                              void* d_out, int out_size, void* d_ws, size_t ws_size,
                              hipStream_t stream) {
    const float* x    = (const float*)d_in[0];
    const int*   fidx = (const int*)d_in[1];
    const float* pi   = (const float*)d_in[2];
    float* prob  = (float*)d_out;                              // B*T
    float* probs = (float*)d_out + (size_t)NBATCH * NTREE;     // B*L*T

    dim3 grid(GRID), block(THREADS);
    hipLaunchKernelGGL(forest_kernel, grid, block, 0, stream,
                       x, fidx, pi, prob, probs);
}

// Round 5
// 142.515 us; speedup vs baseline: 1.2250x; 1.0302x over previous
//
#include <hip/hip_runtime.h>
#include <hip/hip_fp16.h>

#define NTREE  64
#define NFEAT  1024
#define NLEAF  64
#define NBATCH 32768
#define WAVES  4
#define THREADS 256
#define GRID   2048
#define WSTRIDE (GRID * WAVES)   // 8192 waves -> 4 rows each, block-strided

// d[j] = sigmoid(x[b, fidx[t, j]]); layer k uses d[(2^k-1)+i] for parent i;
// child 2i *= d, child 2i+1 *= (1-d). prob = mu . pi[t]; probs[b][l][t] = mu[l].
__device__ __forceinline__ float sig1(float v) {
    return __builtin_amdgcn_rcpf(1.0f + __expf(-v));
}

__global__ __launch_bounds__(THREADS)
void forest_kernel(const float* __restrict__ x,
                   const int*   __restrict__ fidx,
                   const float* __restrict__ pi,
                   float* __restrict__ prob,    // [B][T]
                   float* __restrict__ probs)   // [B][L][T]
{
    __shared__ float    srow[WAVES][NFEAT]; // 16384 B (per-wave private row)
    __shared__ unsigned idxp[32 * 64];      // 8192 B: [pair][t], two u16 byte-offsets
    __shared__ __half2  pil[32 * 64];       // 8192 B: [k][t] = (pi2k-pi2k1, pi2k1)
    // total 32.6 KB

    const int tid  = threadIdx.x;
    const int wid  = tid >> 6;
    const int lane = tid & 63;              // lane == tree t

    // One-time staging (L2-resident inputs).
    for (int i = tid; i < 32 * 64; i += THREADS) {
        int k = i >> 6, t = i & 63;
        unsigned v0 = (unsigned)fidx[t * 63 + 2 * k] << 2;
        unsigned v1 = (2 * k + 1 < 63) ? ((unsigned)fidx[t * 63 + 2 * k + 1] << 2) : 0u;
        idxp[i] = v0 | (v1 << 16);
    }
    for (int i = tid; i < 32 * 64; i += THREADS) {
        int k = i >> 6, t = i & 63;
        float p0 = pi[t * 64 + 2 * k], p1 = pi[t * 64 + 2 * k + 1];
        pil[i] = __floats2half2_rn(p0 - p1, p1);
    }
    __syncthreads();

    const int t = lane;
    const char* swc = reinterpret_cast<const char*>(&srow[wid][0]);
    float4* sr4 = reinterpret_cast<float4*>(&srow[wid][0]);

    // Node c's byte offset: lo/hi half of pair c>>1 (extraction is compile-time
    // selected under full unroll; pair reads CSE within a barrier region).
#define GATH(c) (*reinterpret_cast<const float*>(swc + ((c) & 1                    \
                    ? (idxp[((c) >> 1) * 64 + t] >> 16)                            \
                    : (idxp[((c) >> 1) * 64 + t] & 0xFFFFu))))

    for (int b = blockIdx.x * WAVES + wid; b < NBATCH; b += WSTRIDE) {
        // ---- sigmoid(x[b,:]) -> this wave's private LDS row ----
        const float4* xr4 = reinterpret_cast<const float4*>(x + (size_t)b * NFEAT);
        #pragma unroll
        for (int i = 0; i < 4; ++i) {
            float4 v = xr4[lane + i * 64];
            sr4[lane + i * 64] =
                make_float4(sig1(v.x), sig1(v.y), sig1(v.z), sig1(v.w));
        }
        // Full-block barrier: convoys the 4 waves' read phase, and (as a memory
        // fence) keeps idxp/pil LDS reads inside the loop (no hoist->no spill).
        __syncthreads();

        // ---- layers 0..4: in-place doubling, mu[0..31] ----
        float mu[32];
        mu[0] = 1.0f;
        #pragma unroll
        for (int k = 0; k < 5; ++k) {
            const int n = 1 << k;
            #pragma unroll
            for (int i = n - 1; i >= 0; --i) {
                float dv = GATH(n - 1 + i);
                float m  = mu[i];
                float a  = m * dv;
                mu[2 * i]     = a;
                mu[2 * i + 1] = m - a;
            }
        }

        // ---- final layer fused with coalesced stores + folded pi-dot ----
        float acc = 0.0f;
        float* pb = probs + (size_t)b * (NLEAF * NTREE) + t;
        #pragma unroll
        for (int i = 0; i < 32; ++i) {
            float dv = GATH(31 + i);
            float m  = mu[i];
            float a  = m * dv;            // leaf 2i
            float c  = m - a;             // leaf 2i+1
            pb[(2 * i) * NTREE]     = a;  // 64 lanes span t: 256B coalesced
            pb[(2 * i + 1) * NTREE] = c;
            float2 p = __half22float2(pil[i * 64 + t]);  // (dpi, spi), conflict-free
            acc = fmaf(m, fmaf(dv, p.x, p.y), acc);
        }
        prob[b * NTREE + t] = acc;

        // Convoy the store phase / WAR-protect srow for the next iteration.
        __syncthreads();
    }
#undef GATH
}

extern "C" void kernel_launch(void* const* d_in, const int* in_sizes, int n_in,
                              void* d_out, int out_size, void* d_ws, size_t ws_size,
                              hipStream_t stream) {
    const float* x    = (const float*)d_in[0];
    const int*   fidx = (const int*)d_in[1];
    const float* pi   = (const float*)d_in[2];
    float* prob  = (float*)d_out;                              // B*T
    float* probs = (float*)d_out + (size_t)NBATCH * NTREE;     // B*L*T

    dim3 grid(GRID), block(THREADS);
    hipLaunchKernelGGL(forest_kernel, grid, block, 0, stream,
                       x, fidx, pi, prob, probs);
}

// Round 7
// 136.705 us; speedup vs baseline: 1.2771x; 1.0425x over previous
//
#include <hip/hip_runtime.h>

#define NTREE  64
#define NFEAT  1024
#define NLEAF  64
#define NBATCH 32768
#define WAVES  4
#define THREADS 256

typedef float f32x4 __attribute__((ext_vector_type(4)));

// d[j] = sigmoid(x[b, fidx[t, j]]); layer k uses d[(2^k-1)+i] for parent i;
// child 2i *= d, child 2i+1 *= (1-d). prob = mu . pi[t]; probs[b][l][t] = mu[l].
__global__ __launch_bounds__(THREADS)
void forest_kernel(const float* __restrict__ x,
                   const int*   __restrict__ fidx,
                   const float* __restrict__ pi,
                   float* __restrict__ prob,    // [B][T]
                   float* __restrict__ probs)   // [B][L][T]
{
    __shared__ float srow[WAVES][NFEAT];     // sigmoid of one x-row per wave (16 KB)
    __shared__ int   idxl[NTREE * 63];       // feature indices            (15.75 KB)
    __shared__ float pil[NTREE * 65];        // pi, padded stride 65       (16.25 KB)

    const int tid  = threadIdx.x;
    const int wid  = tid >> 6;
    const int lane = tid & 63;               // lane == tree index t

    // Stage fidx and pi once per block (L2-resident, cheap).
    for (int i = tid; i < NTREE * 63; i += THREADS) idxl[i] = fidx[i];
    for (int i = tid; i < NTREE * NLEAF; i += THREADS)
        pil[(i >> 6) * 65 + (i & 63)] = pi[i];
    __syncthreads();

    const int wavestride = gridDim.x * WAVES;
    for (int b = blockIdx.x * WAVES + wid; b < NBATCH; b += wavestride) {
        // ---- Stage sigmoid(x[b,:]) into this wave's LDS row (nt 16B loads:
        //      x is touch-once, bypass cache allocation) ----
        const f32x4* xr4 = reinterpret_cast<const f32x4*>(x + (size_t)b * NFEAT);
        float4* sr4 = reinterpret_cast<float4*>(&srow[wid][0]);
        #pragma unroll
        for (int i = 0; i < NFEAT / (64 * 4); ++i) {
            f32x4 v = __builtin_nontemporal_load(&xr4[lane + i * 64]);
            float4 s;
            s.x = 1.0f / (1.0f + __expf(-v.x));
            s.y = 1.0f / (1.0f + __expf(-v.y));
            s.z = 1.0f / (1.0f + __expf(-v.z));
            s.w = 1.0f / (1.0f + __expf(-v.w));
            sr4[lane + i * 64] = s;
        }
        __syncthreads();

        const int t = lane;
        const float* sw = &srow[wid][0];
        const int ib = t * 63;
        const int ip = t * 65;

        // ---- Layers 0..4: in-place doubling, mu[0..31] = level-5 interior probs ----
        float mu[32];
        mu[0] = 1.0f;
        #pragma unroll
        for (int k = 0; k < 5; ++k) {
            const int n = 1 << k;
            #pragma unroll
            for (int i = n - 1; i >= 0; --i) {
                float dv = sw[idxl[ib + (n - 1) + i]];
                float m  = mu[i];
                float a  = m * dv;
                mu[2 * i]     = a;        // child 2i:   * d
                mu[2 * i + 1] = m - a;    // child 2i+1: * (1-d)
            }
        }

        // ---- Final layer fused with nt stores + pi-dot epilogue (probs/prob are
        //      write-once, never re-read: bypass cache allocation) ----
        float acc = 0.0f;
        float* pb = probs + (size_t)b * (NLEAF * NTREE) + t;
        #pragma unroll
        for (int i = 0; i < 32; ++i) {
            float dv = sw[idxl[ib + 31 + i]];
            float m  = mu[i];
            float a  = m * dv;      // leaf 2i
            float c  = m - a;       // leaf 2i+1
            __builtin_nontemporal_store(a, &pb[(2 * i) * NTREE]);   // 256B coalesced
            __builtin_nontemporal_store(c, &pb[(2 * i + 1) * NTREE]);
            acc = fmaf(a, pil[ip + 2 * i], acc);
            acc = fmaf(c, pil[ip + 2 * i + 1], acc);
        }
        __builtin_nontemporal_store(acc, &prob[b * NTREE + t]);
        __syncthreads();   // srow[wid] reused next row; uniform trip count
    }
}

extern "C" void kernel_launch(void* const* d_in, const int* in_sizes, int n_in,
                              void* d_out, int out_size, void* d_ws, size_t ws_size,
                              hipStream_t stream) {
    const float* x    = (const float*)d_in[0];
    const int*   fidx = (const int*)d_in[1];
    const float* pi   = (const float*)d_in[2];
    float* prob  = (float*)d_out;                              // B*T
    float* probs = (float*)d_out + (size_t)NBATCH * NTREE;     // B*L*T

    dim3 grid(2048), block(THREADS);
    hipLaunchKernelGGL(forest_kernel, grid, block, 0, stream,
                       x, fidx, pi, prob, probs);
}